// Round 1
// baseline (5232.557 us; speedup 1.0000x reference)
//
#include <hip/hip_runtime.h>

#define N_NODES     8192
#define N_FEAT      1024
#define N_FILT      4
#define MAXDEG      8

// ---------------------------------------------------------------------------
// Kernel A: filt = relu(X @ W1^T + b1) @ W2^T + b2     -> (N_NODES, 4)
// 1024 blocks x 256 threads; 8 nodes/block, 32 lanes per node (one per hidden h)
// ---------------------------------------------------------------------------
__global__ __launch_bounds__(256) void filt_kernel(
    const float* __restrict__ X, const float* __restrict__ W1,
    const float* __restrict__ b1, const float* __restrict__ W2,
    const float* __restrict__ b2, float* __restrict__ filt)
{
    const int node = blockIdx.x * 8 + (threadIdx.x >> 5);
    const int h    = threadIdx.x & 31;
    const float* xr = X  + (size_t)node * N_FEAT;
    const float* wr = W1 + (size_t)h    * N_FEAT;
    float acc = 0.f;
    for (int j = 0; j < N_FEAT; j += 4) {
        float4 xv = *reinterpret_cast<const float4*>(xr + j);
        float4 wv = *reinterpret_cast<const float4*>(wr + j);
        acc += xv.x * wv.x + xv.y * wv.y + xv.z * wv.z + xv.w * wv.w;
    }
    float hv = fmaxf(acc + b1[h], 0.f);
    #pragma unroll
    for (int fo = 0; fo < N_FILT; ++fo) {
        float v = hv * W2[fo * 32 + h];
        // reduce within the 32-lane group
        for (int off = 16; off; off >>= 1) v += __shfl_xor(v, off, 32);
        if (h == 0) filt[node * N_FILT + fo] = v + b2[fo];
    }
}

// ---------------------------------------------------------------------------
// Kernel W: wsum[j] = sum_h Wt[h][j] (j=0..7), wsum[8] = sum_h bt[h]
// ---------------------------------------------------------------------------
__global__ void wsum_kernel(const float* __restrict__ Wt,
                            const float* __restrict__ bt,
                            float* __restrict__ wsum)
{
    int t = threadIdx.x;
    if (t < 8) {
        float s = 0.f;
        for (int hh = 0; hh < 64; ++hh) s += Wt[hh * 8 + t];
        wsum[t] = s;
    } else if (t == 8) {
        float s = 0.f;
        for (int hh = 0; hh < 64; ++hh) s += bt[hh];
        wsum[8] = s;
    }
}

// ---------------------------------------------------------------------------
// Kernel B: per-filtration 0-dim persistence.
// 4 blocks (one per filtration) x 256 threads.
// Phase 1: load values; Phase 2: bitonic sort (value, idx) ascending (stable
// via idx tiebreak, matches jnp.argsort); Phase 3: init pos/parent/death;
// Phase 4: wave-serial union-find, batched per step (star merges are
// order-independent within a step); Phase 5: write pos/death per node.
//
// LDS layout (64 KB total, s_val region reused for parent/death after sort):
//   [0,32768)      float  s_val[8192]   (sort)   ->  u16 parent[8192] | u16 death[8192]
//   [32768,49152)  u16    s_idx[8192]   (order after sort)
//   [49152,65536)  u16    s_pos[8192]
// ---------------------------------------------------------------------------
__global__ __launch_bounds__(256) void persist_kernel(
    const float* __restrict__ filt,      // [N_NODES][4]
    const int*   __restrict__ edge_dst,  // [N_NODES*8]
    float* __restrict__ posd)            // [(2*f+0)*N][n]=pos, [(2*f+1)*N][n]=death
{
    const int f   = blockIdx.x;
    const int tid = threadIdx.x;

    __shared__ __align__(16) unsigned char smem[65536];
    float*          s_val    = reinterpret_cast<float*>(smem);
    unsigned short* s_parent = reinterpret_cast<unsigned short*>(smem);
    unsigned short* s_death  = reinterpret_cast<unsigned short*>(smem + 16384);
    unsigned short* s_idx    = reinterpret_cast<unsigned short*>(smem + 32768);
    unsigned short* s_pos    = reinterpret_cast<unsigned short*>(smem + 49152);

    for (int v = tid; v < N_NODES; v += 256) {
        s_val[v] = filt[v * N_FILT + f];
        s_idx[v] = (unsigned short)v;
    }
    __syncthreads();

    // Bitonic sort, ascending by (value, idx)
    for (int k = 2; k <= N_NODES; k <<= 1) {
        for (int j = k >> 1; j > 0; j >>= 1) {
            for (int t = tid; t < N_NODES / 2; t += 256) {
                int i = ((t & ~(j - 1)) << 1) | (t & (j - 1)); // (i & j) == 0
                int p = i | j;
                bool up = ((i & k) == 0);
                float va = s_val[i], vb = s_val[p];
                unsigned short ia = s_idx[i], ib = s_idx[p];
                bool agtb = (va > vb) || (va == vb && ia > ib);
                if (agtb == up) {
                    s_val[i] = vb; s_val[p] = va;
                    s_idx[i] = ib; s_idx[p] = ia;
                }
            }
            __syncthreads();
        }
    }

    // init pos / parent / death (parent,death reuse s_val's bytes)
    for (int v = tid; v < N_NODES; v += 256) {
        s_pos[s_idx[v]]  = (unsigned short)v;
        s_parent[v]      = (unsigned short)v;
        s_death[v]       = 0;
    }
    __syncthreads();

    // Serial sweep over filtration steps; wave 0 only.
    if (tid < 64) {
        const int lane = tid;
        int vertex = s_idx[0];
        int nb = (lane < MAXDEG) ? edge_dst[vertex * MAXDEG + lane] : 0;
        for (int s = 0; s < N_NODES; ++s) {
            // prefetch next step's neighbors
            int vnext = (s + 1 < N_NODES) ? (int)s_idx[s + 1] : 0;
            int nb_next = (lane < MAXDEG) ? edge_dst[vnext * MAXDEG + lane] : 0;

            // per-lane find source: valid out-neighbors, else the new vertex
            int x = vertex;
            if (lane < MAXDEG) {
                int u = nb;
                if ((int)s_pos[u] <= s) x = u;
            }
            // lockstep parallel find (all 64 lanes; inactive lanes chase vertex)
            int p = x;
            for (;;) {
                int q = (int)s_parent[p];
                if (__all((int)(q == p))) break;
                p = q;
            }
            // path compression
            s_parent[x] = (unsigned short)p;
            // elder = root with minimum position among the merge set
            int key = (((int)s_pos[p]) << 13) | p;   // pos,root each < 8192
            int m = key;
            for (int off = 32; off; off >>= 1) m = min(m, __shfl_xor(m, off));
            int elder = m & 0x1FFF;
            if (p != elder) {
                // this root dies at step s (duplicate lanes write same values)
                s_death[s_pos[p]]  = (unsigned short)s;
                s_parent[p] = (unsigned short)elder;
            }
            vertex = vnext;
            nb = nb_next;
        }
    }
    __syncthreads();

    // Emit per-node (birth=pos, death); death==0 -> N_NODES (undying)
    for (int n = tid; n < N_NODES; n += 256) {
        int p = (int)s_pos[n];
        int d = (int)s_death[p];
        posd[(2 * f + 0) * N_NODES + n] = (float)p;
        posd[(2 * f + 1) * N_NODES + n] = d ? (float)d : (float)N_NODES;
    }
}

// ---------------------------------------------------------------------------
// Kernel P: pooled[n] = wsum[8] + sum_i pos_i[n]*wsum[2i] + death_i[n]*wsum[2i+1]
// ---------------------------------------------------------------------------
__global__ __launch_bounds__(256) void pooled_kernel(
    const float* __restrict__ posd, const float* __restrict__ wsum,
    float* __restrict__ pooled)
{
    int n = blockIdx.x * 256 + threadIdx.x;
    float acc = wsum[8];
    #pragma unroll
    for (int i = 0; i < N_FILT; ++i) {
        acc += posd[(2 * i + 0) * N_NODES + n] * wsum[2 * i + 0]
             + posd[(2 * i + 1) * N_NODES + n] * wsum[2 * i + 1];
    }
    pooled[n] = acc;
}

// ---------------------------------------------------------------------------
// Kernel C: out[n][f] = X[n][f] + pooled[n]*Wr[f] + br[f]
// 8192 blocks x 256 threads, float4 per thread
// ---------------------------------------------------------------------------
__global__ __launch_bounds__(256) void out_kernel(
    const float* __restrict__ X, const float* __restrict__ Wr,
    const float* __restrict__ br, const float* __restrict__ pooled,
    float* __restrict__ out)
{
    const int node = blockIdx.x;
    const float pl = pooled[node];
    const int fb = threadIdx.x * 4;
    const float4 xv = *reinterpret_cast<const float4*>(X + (size_t)node * N_FEAT + fb);
    const float4 wv = *reinterpret_cast<const float4*>(Wr + fb);
    const float4 bv = *reinterpret_cast<const float4*>(br + fb);
    float4 o;
    o.x = xv.x + pl * wv.x + bv.x;
    o.y = xv.y + pl * wv.y + bv.y;
    o.z = xv.z + pl * wv.z + bv.z;
    o.w = xv.w + pl * wv.w + bv.w;
    *reinterpret_cast<float4*>(out + (size_t)node * N_FEAT + fb) = o;
}

// ---------------------------------------------------------------------------
extern "C" void kernel_launch(void* const* d_in, const int* in_sizes, int n_in,
                              void* d_out, int out_size, void* d_ws, size_t ws_size,
                              hipStream_t stream) {
    const float* X  = (const float*)d_in[0];
    const int* edge = (const int*)d_in[1];
    const float* W1 = (const float*)d_in[2];
    const float* b1 = (const float*)d_in[3];
    const float* W2 = (const float*)d_in[4];
    const float* b2 = (const float*)d_in[5];
    const float* Wt = (const float*)d_in[6];
    const float* bt = (const float*)d_in[7];
    const float* Wr = (const float*)d_in[8];
    const float* br = (const float*)d_in[9];

    // edge_list is (2, N_EDGES) row-major: row 0 = src (= repeat(arange, 8)),
    // row 1 = dst.  nbr_table[v][k] == dst[8v+k] (src sorted, exactly 8/node).
    const int* edge_dst = edge + N_NODES * MAXDEG;

    float* ws     = (float*)d_ws;
    float* filt   = ws;                       // 32768 floats (128 KB)
    float* posd   = ws + 32768;               // 65536 floats (256 KB)
    float* wsum   = ws + 32768 + 65536;       // 16 floats
    float* pooled = wsum + 16;                // 8192 floats

    hipLaunchKernelGGL(filt_kernel,  dim3(N_NODES / 8), dim3(256), 0, stream,
                       X, W1, b1, W2, b2, filt);
    hipLaunchKernelGGL(wsum_kernel,  dim3(1), dim3(64), 0, stream, Wt, bt, wsum);
    hipLaunchKernelGGL(persist_kernel, dim3(N_FILT), dim3(256), 0, stream,
                       filt, edge_dst, posd);
    hipLaunchKernelGGL(pooled_kernel, dim3(N_NODES / 256), dim3(256), 0, stream,
                       posd, wsum, pooled);
    hipLaunchKernelGGL(out_kernel,   dim3(N_NODES), dim3(256), 0, stream,
                       X, Wr, br, pooled, (float*)d_out);
}

// Round 2
// 2613.068 us; speedup vs baseline: 2.0025x; 2.0025x over previous
//
#include <hip/hip_runtime.h>

#define N_NODES     8192
#define N_FEAT      1024
#define N_FILT      4
#define MAXDEG      8

// ---------------------------------------------------------------------------
// Kernel A: filt = relu(X @ W1^T + b1) @ W2^T + b2     -> (N_NODES, 4)
// ---------------------------------------------------------------------------
__global__ __launch_bounds__(256) void filt_kernel(
    const float* __restrict__ X, const float* __restrict__ W1,
    const float* __restrict__ b1, const float* __restrict__ W2,
    const float* __restrict__ b2, float* __restrict__ filt)
{
    const int node = blockIdx.x * 8 + (threadIdx.x >> 5);
    const int h    = threadIdx.x & 31;
    const float* xr = X  + (size_t)node * N_FEAT;
    const float* wr = W1 + (size_t)h    * N_FEAT;
    float acc = 0.f;
    for (int j = 0; j < N_FEAT; j += 4) {
        float4 xv = *reinterpret_cast<const float4*>(xr + j);
        float4 wv = *reinterpret_cast<const float4*>(wr + j);
        acc += xv.x * wv.x + xv.y * wv.y + xv.z * wv.z + xv.w * wv.w;
    }
    float hv = fmaxf(acc + b1[h], 0.f);
    #pragma unroll
    for (int fo = 0; fo < N_FILT; ++fo) {
        float v = hv * W2[fo * 32 + h];
        for (int off = 16; off; off >>= 1) v += __shfl_xor(v, off, 32);
        if (h == 0) filt[node * N_FILT + fo] = v + b2[fo];
    }
}

// ---------------------------------------------------------------------------
// Kernel W: wsum[j] = sum_h Wt[h][j] (j=0..7), wsum[8] = sum_h bt[h]
// ---------------------------------------------------------------------------
__global__ void wsum_kernel(const float* __restrict__ Wt,
                            const float* __restrict__ bt,
                            float* __restrict__ wsum)
{
    int t = threadIdx.x;
    if (t < 8) {
        float s = 0.f;
        for (int hh = 0; hh < 64; ++hh) s += Wt[hh * 8 + t];
        wsum[t] = s;
    } else if (t == 8) {
        float s = 0.f;
        for (int hh = 0; hh < 64; ++hh) s += bt[hh];
        wsum[8] = s;
    }
}

// ---------------------------------------------------------------------------
// Kernel B: per-filtration 0-dim persistence, pos-space union-find.
// 4 blocks x 256 threads. Phases:
//  1. load values, bitonic sort (value, idx) ascending (stable)
//  2. pos[] from order
//  3. parallel static edge filter: et[s][k] = min(pos[nbr_k(order[s])], s)
//     (written to global ws; also init parent/death, aliasing the sort buffer)
//  4. wave 0: serial batched union-find over steps (register ring prefetch
//     of et, readlane min-reduce, compress-to-elder).
//     waves 1-3: racy-but-monotone background path compression (volatile).
//  5. emit u16 (pos, death) per node.
// ---------------------------------------------------------------------------

#define SERIAL_STEP(sv, buf)                                                   \
    do {                                                                       \
        int x_ = (lane < 8) ? (int)(buf) : (sv);                               \
        int p_ = x_;                                                           \
        for (;;) {                                                             \
            int q_ = s_par[p_];                                                \
            if (__all(q_ == p_)) break;                                        \
            p_ = q_;                                                           \
        }                                                                      \
        int m0_ = min(__builtin_amdgcn_readlane(p_, 0),                        \
                      __builtin_amdgcn_readlane(p_, 1));                       \
        int m1_ = min(__builtin_amdgcn_readlane(p_, 2),                        \
                      __builtin_amdgcn_readlane(p_, 3));                       \
        int m2_ = min(__builtin_amdgcn_readlane(p_, 4),                        \
                      __builtin_amdgcn_readlane(p_, 5));                       \
        int m3_ = min(__builtin_amdgcn_readlane(p_, 6),                        \
                      __builtin_amdgcn_readlane(p_, 7));                       \
        int mm_ = min(min(m0_, m1_), min(m2_, m3_));                           \
        if (mm_ > (sv)) mm_ = (sv);                                            \
        if (lane < 9) {                                                        \
            s_par[x_] = (unsigned short)mm_;                                   \
            if (p_ != mm_) {                                                   \
                s_dth[p_] = (unsigned short)(sv);                              \
                s_par[p_] = (unsigned short)mm_;                               \
            }                                                                  \
        }                                                                      \
    } while (0)

__global__ __launch_bounds__(256) void persist_kernel(
    const float* __restrict__ filt,       // [N_NODES][4]
    const int*   __restrict__ edge_dst,   // [N_NODES*8]
    unsigned short* __restrict__ ews,     // [N_FILT][N_NODES*8] step-edge table
    unsigned short* __restrict__ posd16)  // [N_FILT][2][N_NODES] (pos, death)
{
    const int f   = blockIdx.x;
    const int tid = threadIdx.x;

    __shared__ __align__(16) unsigned char smem[65536];
    float*          s_val = reinterpret_cast<float*>(smem);
    volatile unsigned short* s_par =
        reinterpret_cast<volatile unsigned short*>(smem);          // 16 KB (aliases s_val)
    unsigned short* s_dth = reinterpret_cast<unsigned short*>(smem + 16384);
    unsigned short* s_idx = reinterpret_cast<unsigned short*>(smem + 32768);
    unsigned short* s_pos = reinterpret_cast<unsigned short*>(smem + 49152);
    volatile int*   s_done = reinterpret_cast<volatile int*>(smem + 32768); // aliases s_idx[0:2]

    // ---- phase 1: load + bitonic sort (value, idx) ----
    for (int v = tid; v < N_NODES; v += 256) {
        s_val[v] = filt[v * N_FILT + f];
        s_idx[v] = (unsigned short)v;
    }
    __syncthreads();
    for (int k = 2; k <= N_NODES; k <<= 1) {
        for (int j = k >> 1; j > 0; j >>= 1) {
            for (int t = tid; t < N_NODES / 2; t += 256) {
                int i = ((t & ~(j - 1)) << 1) | (t & (j - 1));
                int p = i | j;
                bool up = ((i & k) == 0);
                float va = s_val[i], vb = s_val[p];
                unsigned short ia = s_idx[i], ib = s_idx[p];
                bool agtb = (va > vb) || (va == vb && ia > ib);
                if (agtb == up) {
                    s_val[i] = vb; s_val[p] = va;
                    s_idx[i] = ib; s_idx[p] = ia;
                }
            }
            __syncthreads();
        }
    }

    // ---- phase 2: pos ----
    for (int v = tid; v < N_NODES; v += 256)
        s_pos[s_idx[v]] = (unsigned short)v;
    __syncthreads();

    // ---- phase 3: static edge filter into global ws + init parent/death ----
    unsigned short* et = ews + (size_t)f * (N_NODES * MAXDEG);
    for (int e = tid; e < N_NODES * MAXDEG; e += 256) {
        int s = e >> 3, k = e & 7;
        int v = (int)s_idx[s];
        int u = edge_dst[v * MAXDEG + k];
        int q = (int)s_pos[u];
        et[e] = (unsigned short)(q < s ? q : s);   // invalid/self -> s
    }
    for (int v = tid; v < N_NODES; v += 256) {
        reinterpret_cast<unsigned short*>(smem)[v] = (unsigned short)v; // parent
        s_dth[v] = 0;
    }
    __syncthreads();
    if (tid == 0) *s_done = 0;
    __syncthreads();

    // ---- phase 4: serial union-find (wave 0) + background compression ----
    if (tid < 64) {
        const int lane = tid;
        const unsigned short* etl = et + (lane & 7);
        int b0 = (int)etl[0 * 8];
        int b1 = (int)etl[1 * 8];
        int b2 = (int)etl[2 * 8];
        int b3 = (int)etl[3 * 8];
        for (int s = 0; s < N_NODES; s += 4) {
            int nx;
            SERIAL_STEP(s + 0, b0);
            nx = (s + 4 < N_NODES) ? s + 4 : N_NODES - 1; b0 = (int)etl[nx * 8];
            SERIAL_STEP(s + 1, b1);
            nx = (s + 5 < N_NODES) ? s + 5 : N_NODES - 1; b1 = (int)etl[nx * 8];
            SERIAL_STEP(s + 2, b2);
            nx = (s + 6 < N_NODES) ? s + 6 : N_NODES - 1; b2 = (int)etl[nx * 8];
            SERIAL_STEP(s + 3, b3);
            nx = (s + 7 < N_NODES) ? s + 7 : N_NODES - 1; b3 = (int)etl[nx * 8];
        }
        if (lane == 0) *s_done = 1;
    } else {
        // monotone lock-free pointer halving; 'g != p' guard avoids the
        // root no-op write that could clobber a concurrent union.
        while (!(*s_done)) {
            for (int v = tid - 64; v < N_NODES; v += 192) {
                int p = (int)s_par[v];
                int g = (int)s_par[p];
                if (g != p) s_par[v] = (unsigned short)g;
            }
            __builtin_amdgcn_s_sleep(2);
        }
    }
    __syncthreads();

    // ---- phase 5: emit (pos, death) as u16; death 0 -> N ----
    unsigned short* pd = posd16 + (size_t)f * (2 * N_NODES);
    for (int n = tid; n < N_NODES; n += 256) {
        int p = (int)s_pos[n];
        int d = (int)s_dth[p];
        pd[n]            = (unsigned short)p;
        pd[N_NODES + n]  = (unsigned short)(d ? d : N_NODES);
    }
}

// ---------------------------------------------------------------------------
// Kernel P: pooled[n] = wsum[8] + sum_f pos_f[n]*wsum[2f] + death_f[n]*wsum[2f+1]
// ---------------------------------------------------------------------------
__global__ __launch_bounds__(256) void pooled_kernel(
    const unsigned short* __restrict__ posd16, const float* __restrict__ wsum,
    float* __restrict__ pooled)
{
    int n = blockIdx.x * 256 + threadIdx.x;
    float acc = wsum[8];
    #pragma unroll
    for (int i = 0; i < N_FILT; ++i) {
        acc += (float)posd16[i * 2 * N_NODES + n]           * wsum[2 * i + 0]
             + (float)posd16[i * 2 * N_NODES + N_NODES + n] * wsum[2 * i + 1];
    }
    pooled[n] = acc;
}

// ---------------------------------------------------------------------------
// Kernel C: out[n][f] = X[n][f] + pooled[n]*Wr[f] + br[f]
// ---------------------------------------------------------------------------
__global__ __launch_bounds__(256) void out_kernel(
    const float* __restrict__ X, const float* __restrict__ Wr,
    const float* __restrict__ br, const float* __restrict__ pooled,
    float* __restrict__ out)
{
    const int node = blockIdx.x;
    const float pl = pooled[node];
    const int fb = threadIdx.x * 4;
    const float4 xv = *reinterpret_cast<const float4*>(X + (size_t)node * N_FEAT + fb);
    const float4 wv = *reinterpret_cast<const float4*>(Wr + fb);
    const float4 bv = *reinterpret_cast<const float4*>(br + fb);
    float4 o;
    o.x = xv.x + pl * wv.x + bv.x;
    o.y = xv.y + pl * wv.y + bv.y;
    o.z = xv.z + pl * wv.z + bv.z;
    o.w = xv.w + pl * wv.w + bv.w;
    *reinterpret_cast<float4*>(out + (size_t)node * N_FEAT + fb) = o;
}

// ---------------------------------------------------------------------------
extern "C" void kernel_launch(void* const* d_in, const int* in_sizes, int n_in,
                              void* d_out, int out_size, void* d_ws, size_t ws_size,
                              hipStream_t stream) {
    const float* X  = (const float*)d_in[0];
    const int* edge = (const int*)d_in[1];
    const float* W1 = (const float*)d_in[2];
    const float* b1 = (const float*)d_in[3];
    const float* W2 = (const float*)d_in[4];
    const float* b2 = (const float*)d_in[5];
    const float* Wt = (const float*)d_in[6];
    const float* bt = (const float*)d_in[7];
    const float* Wr = (const float*)d_in[8];
    const float* br = (const float*)d_in[9];

    const int* edge_dst = edge + N_NODES * MAXDEG;  // row 1 of edge_list

    // ws layout (bytes):
    //   [0,        131072)  filt   f32[8192*4]
    //   [131072,   655360)  ews    u16[4][65536]
    //   [655360,   786432)  posd16 u16[4][2][8192]
    //   [786432,   786496)  wsum   f32[16]
    //   [786496,   819264)  pooled f32[8192]
    char* wsb = (char*)d_ws;
    float*          filt   = (float*)(wsb);
    unsigned short* ews    = (unsigned short*)(wsb + 131072);
    unsigned short* posd16 = (unsigned short*)(wsb + 655360);
    float*          wsum   = (float*)(wsb + 786432);
    float*          pooled = (float*)(wsb + 786496);

    hipLaunchKernelGGL(filt_kernel,  dim3(N_NODES / 8), dim3(256), 0, stream,
                       X, W1, b1, W2, b2, filt);
    hipLaunchKernelGGL(wsum_kernel,  dim3(1), dim3(64), 0, stream, Wt, bt, wsum);
    hipLaunchKernelGGL(persist_kernel, dim3(N_FILT), dim3(256), 0, stream,
                       filt, edge_dst, ews, posd16);
    hipLaunchKernelGGL(pooled_kernel, dim3(N_NODES / 256), dim3(256), 0, stream,
                       posd16, wsum, pooled);
    hipLaunchKernelGGL(out_kernel,   dim3(N_NODES), dim3(256), 0, stream,
                       X, Wr, br, pooled, (float*)d_out);
}